// Round 9
// baseline (248.803 us; speedup 1.0000x reference)
//
#include <hip/hip_runtime.h>
#include <hip/hip_fp16.h>
#include <math.h>

#define N_NODES 20000
#define N_EDGES 160000
#define EPSV 1e-12f
#define SLOPE 0.2f
#define LOG2E 1.4426950408889634f

__device__ __forceinline__ float leaky(float x) { return x >= 0.f ? x : SLOPE * x; }

__device__ __forceinline__ unsigned short cvt_bf16(float f) {
    unsigned u = __float_as_uint(f);
    u = (u + 0x7FFFu + ((u >> 16) & 1u)) >> 16;
    return (unsigned short)u;
}
__device__ __forceinline__ unsigned pk2(float a, float b) {
    return (unsigned)cvt_bf16(a) | ((unsigned)cvt_bf16(b) << 16);
}

typedef __attribute__((ext_vector_type(8))) short bf16x8;
typedef __attribute__((ext_vector_type(4))) float f32x4;

// ============ STAGE 1: fold (0..271) + rel (272) + count (273..912) ============
__global__ __launch_bounds__(256) void k_pre(
    const float* __restrict__ Wv, const float* __restrict__ Wn,
    const float* __restrict__ nbb, const float* __restrict__ wsrc,
    const float* __restrict__ wtgt, const float* __restrict__ gw,
    unsigned short* __restrict__ Bt, float* __restrict__ bg2,
    const float* __restrict__ Wrel, const float* __restrict__ wrel,
    const float* __restrict__ deprel_emb, const float* __restrict__ deparc_emb,
    float* __restrict__ SA, float* __restrict__ SB,
    const int* __restrict__ tgt, int* __restrict__ cnts)
{
    __shared__ float wr2[128 * 8];
    __shared__ int cnt[250];
    int k = threadIdx.x;
    int b = blockIdx.x;
    if (b < 256) {
        Bt[b * 256 + k] = cvt_bf16(Wv[k * 256 + b]);
    } else if (b < 264) {
        int h = b - 256;
        float a_vs = 0.f, a_vt = 0.f, a_ng = 0.f;
        for (int d = 0; d < 32; ++d) {
            float w = Wv[k * 256 + h * 32 + d];
            a_vs = fmaf(w, wsrc[h * 32 + d], a_vs);
            a_vt = fmaf(w, wtgt[h * 32 + d], a_vt);
        }
        for (int j = 0; j < 256; ++j)
            a_ng = fmaf(Wn[k * 256 + j], gw[(256 + j) * 8 + h], a_ng);
        Bt[(256 + h) * 256 + k] = cvt_bf16(a_vs);
        Bt[(264 + h) * 256 + k] = cvt_bf16(a_vt);
        Bt[(272 + h) * 256 + k] = cvt_bf16(gw[k * 8 + h]);
        Bt[(280 + h) * 256 + k] = cvt_bf16(a_ng);
        if (k == 0) {
            float s = 0.f;
            for (int j = 0; j < 256; ++j) s = fmaf(nbb[j], gw[(256 + j) * 8 + h], s);
            bg2[h] = s;
        }
    } else if (b < 272) {
        int n0 = 288 + (b - 264) * 4;
        for (int i = 0; i < 4; ++i) Bt[(n0 + i) * 256 + k] = 0;
    } else if (b == 272) {
        for (int i = k; i < 1024; i += 256) {
            int kk = i >> 3, h = i & 7;
            float acc = 0.f;
            for (int r = 0; r < 16; ++r)
                acc += Wrel[kk * 128 + h * 16 + r] * wrel[h * 16 + r];
            wr2[kk * 8 + h] = acc;
        }
        __syncthreads();
        for (int i = k; i < 50 * 8; i += 256) {
            int d = i >> 3, h = i & 7;
            float acc = 0.f;
            for (int kk = 0; kk < 64; ++kk) acc += deprel_emb[d * 64 + kk] * wr2[kk * 8 + h];
            SA[i] = acc;
        }
        for (int i = k; i < 4 * 8; i += 256) {
            int d = i >> 3, h = i & 7;
            float acc = 0.f;
            for (int kk = 0; kk < 64; ++kk) acc += deparc_emb[d * 64 + kk] * wr2[(64 + kk) * 8 + h];
            SB[i] = acc;
        }
    } else {
        int idx = b - 273;            // 0..639
        int slice = idx & 7, range = idx >> 3;
        int lo = range * 250;
        if (k < 250) cnt[k] = 0;
        __syncthreads();
        const int4* t4 = (const int4*)tgt;
        int i0 = slice * 5000;
#pragma unroll 4
        for (int i = k; i < 5000; i += 256) {
            int4 v = t4[i0 + i];
            unsigned a = (unsigned)(v.x - lo); if (a < 250u) atomicAdd(&cnt[a], 1);
            unsigned bb = (unsigned)(v.y - lo); if (bb < 250u) atomicAdd(&cnt[bb], 1);
            unsigned c = (unsigned)(v.z - lo); if (c < 250u) atomicAdd(&cnt[c], 1);
            unsigned d = (unsigned)(v.w - lo); if (d < 250u) atomicAdd(&cnt[d], 1);
        }
        __syncthreads();
        if (k < 250) cnts[(lo + k) * 8 + slice] = cnt[k];
    }
}

// ============ STAGE 2: mfma (0..1249) + scan (1250) ============
__global__ __launch_bounds__(256) void k_mid(
    const float* __restrict__ inp, const unsigned short* __restrict__ Bt,
    const float* __restrict__ bg2, __half* __restrict__ valh,
    float* __restrict__ vs, float* __restrict__ vt,
    float* __restrict__ g1, float* __restrict__ g2,
    const int* __restrict__ cnts, int* __restrict__ rowptr)
{
    __shared__ unsigned short degl[N_NODES];  // 40 KB (scan block only)
    __shared__ int wsum[4];
    int tid = threadIdx.x;
    if (blockIdx.x < 1250) {
        int wave = tid >> 6, lane = tid & 63;
        int quad = lane >> 4, l16 = lane & 15;
        int row0 = blockIdx.x * 16;
        const float* arow = inp + (size_t)(row0 + l16) * 256;
        bf16x8 afr[8];
#pragma unroll
        for (int kk = 0; kk < 8; ++kk) {
            float4 f0 = *(const float4*)(arow + kk * 32 + quad * 8);
            float4 f1 = *(const float4*)(arow + kk * 32 + quad * 8 + 4);
            union { unsigned u[4]; bf16x8 v; } cv;
            cv.u[0] = pk2(f0.x, f0.y); cv.u[1] = pk2(f0.z, f0.w);
            cv.u[2] = pk2(f1.x, f1.y); cv.u[3] = pk2(f1.z, f1.w);
            afr[kk] = cv.v;
        }
        f32x4 acc[5] = {};
        const unsigned short* bbase = Bt + (size_t)(wave * 80 + l16) * 256 + quad * 8;
#pragma unroll
        for (int kk = 0; kk < 8; ++kk) {
#pragma unroll
            for (int t = 0; t < 5; ++t) {
                bf16x8 bf = *(const bf16x8*)(bbase + t * 16 * 256 + kk * 32);
                acc[t] = __builtin_amdgcn_mfma_f32_16x16x32_bf16(afr[kk], bf, acc[t], 0, 0, 0);
            }
        }
#pragma unroll
        for (int t = 0; t < 5; ++t) {
            int n = wave * 80 + t * 16 + l16;
#pragma unroll
            for (int r = 0; r < 4; ++r) {
                int row = row0 + quad * 4 + r;
                float v = acc[t][r];
                if (n < 256) {
                    valh[(size_t)row * 256 + n] = __float2half(v);
                } else if (n < 288) {
                    int c2 = n - 256, which = c2 >> 3, h = c2 & 7;
                    if (which == 3) v += bg2[h];
                    float* dst = (which == 0) ? vs : (which == 1) ? vt : (which == 2) ? g1 : g2;
                    dst[(size_t)row * 8 + h] = v;
                }
            }
        }
    } else {
        // 256-thread scan: deg sums -> exclusive rowptr
        int lane = tid & 63, w = tid >> 6;
        for (int nn = tid; nn < N_NODES; nn += 256) {
            const int4* c4 = (const int4*)(cnts + (size_t)nn * 8);
            int4 a = c4[0], b = c4[1];
            degl[nn] = (unsigned short)(a.x + a.y + a.z + a.w + b.x + b.y + b.z + b.w);
        }
        __syncthreads();
        int start = tid * 79;
        int stop = min(start + 79, N_NODES);
        int s = 0;
        for (int i = start; i < stop; ++i) s += degl[i];
        int ps = s;
#pragma unroll
        for (int off = 1; off < 64; off <<= 1) {
            int x = __shfl_up(ps, off, 64);
            if (lane >= off) ps += x;
        }
        if (lane == 63) wsum[w] = ps;
        __syncthreads();
        if (tid == 0) {
            int a0 = wsum[0], a1 = wsum[1], a2 = wsum[2];
            wsum[0] = 0; wsum[1] = a0; wsum[2] = a0 + a1; wsum[3] = a0 + a1 + a2;
        }
        __syncthreads();
        int run = wsum[w] + ps - s;
        for (int i = start; i < stop; ++i) {
            rowptr[i] = run;
            run += degl[i];
        }
        if (tid == 255) rowptr[N_NODES] = run;
    }
}

// ============ STAGE 3: escore (0..624) + fill (625..1264) ============
// fill writes int2 {e, src[e]} -- removes one dependent gather level from k_agg
__global__ __launch_bounds__(256) void k_post(
    const float* __restrict__ vs, const float* __restrict__ vt,
    const float* __restrict__ SA, const float* __restrict__ SB,
    const float* __restrict__ g2,
    const int* __restrict__ src, const int* __restrict__ tgt,
    const int* __restrict__ deprel, const int* __restrict__ deparc,
    float* __restrict__ pw,
    const int* __restrict__ rowptr, const int* __restrict__ cnts,
    int2* __restrict__ eidx2)
{
    __shared__ int cur[250];
    int tid = threadIdx.x;
    if (blockIdx.x < 625) {
        int e = blockIdx.x * 256 + tid;
        int s = src[e], t = tgt[e], dr = deprel[e], da = deparc[e];
        const float4* vs4 = (const float4*)(vs + (size_t)s * 8);
        const float4* vt4 = (const float4*)(vt + (size_t)t * 8);
        const float4* SA4 = (const float4*)(SA + dr * 8);
        const float4* SB4 = (const float4*)(SB + da * 8);
        const float4* g24 = (const float4*)(g2 + (size_t)s * 8);
        float4 a0 = vs4[0], a1 = vs4[1];
        float4 b0 = vt4[0], b1 = vt4[1];
        float4 ra0 = SA4[0], ra1 = SA4[1];
        float4 rb0 = SB4[0], rb1 = SB4[1];
        float4 gg0 = g24[0], gg1 = g24[1];
        float av[8] = {a0.x, a0.y, a0.z, a0.w, a1.x, a1.y, a1.z, a1.w};
        float bv[8] = {b0.x, b0.y, b0.z, b0.w, b1.x, b1.y, b1.z, b1.w};
        float rv[8] = {ra0.x + rb0.x, ra0.y + rb0.y, ra0.z + rb0.z, ra0.w + rb0.w,
                       ra1.x + rb1.x, ra1.y + rb1.y, ra1.z + rb1.z, ra1.w + rb1.w};
        float ev[8], er[8];
#pragma unroll
        for (int h = 0; h < 8; ++h) {
            ev[h] = exp2f(leaky(av[h] + bv[h]) * LOG2E);
            er[h] = exp2f(leaky(rv[h] + bv[h]) * LOG2E);
        }
        float4* o = (float4*)(pw + (size_t)e * 24);
        o[0] = make_float4(ev[0], ev[1], ev[2], ev[3]);
        o[1] = make_float4(ev[4], ev[5], ev[6], ev[7]);
        o[2] = make_float4(er[0], er[1], er[2], er[3]);
        o[3] = make_float4(er[4], er[5], er[6], er[7]);
        o[4] = gg0;
        o[5] = gg1;
    } else {
        int idx = blockIdx.x - 625;
        int slice = idx & 7, range = idx >> 3;
        int lo = range * 250;
        if (tid < 250) {
            int base = rowptr[lo + tid];
            const int* c = cnts + (size_t)(lo + tid) * 8;
            for (int s = 0; s < slice; ++s) base += c[s];
            cur[tid] = base;
        }
        __syncthreads();
        const int4* t4 = (const int4*)tgt;
        const int4* s4 = (const int4*)src;
        int i0 = slice * 5000;
        for (int i = tid; i < 5000; i += 256) {
            int4 v = t4[i0 + i];
            int4 sv = s4[i0 + i];
            int e = (i0 + i) * 4;
            unsigned a = (unsigned)(v.x - lo); if (a < 250u) { int p = atomicAdd(&cur[a], 1); eidx2[p] = make_int2(e, sv.x); }
            unsigned b = (unsigned)(v.y - lo); if (b < 250u) { int p = atomicAdd(&cur[b], 1); eidx2[p] = make_int2(e + 1, sv.y); }
            unsigned c = (unsigned)(v.z - lo); if (c < 250u) { int p = atomicAdd(&cur[c], 1); eidx2[p] = make_int2(e + 2, sv.z); }
            unsigned d = (unsigned)(v.w - lo); if (d < 250u) { int p = atomicAdd(&cur[d], 1); eidx2[p] = make_int2(e + 3, sv.w); }
        }
    }
}

// ============ STAGE 4: per-node aggregation, batch-8 prefetch ============
__global__ __launch_bounds__(256) void k_agg(
    const __half* __restrict__ valh, const float* __restrict__ pw,
    const float* __restrict__ g1,
    const int* __restrict__ rowptr, const int2* __restrict__ eidx2,
    const float* __restrict__ Wp, const float* __restrict__ Pb,
    const float* __restrict__ gate_b, const float* __restrict__ final_bias,
    float* __restrict__ out)
{
    __shared__ float cat[4][548];
    __shared__ float gate_lds[4][8];
    int tid = threadIdx.x, wv = tid >> 6, l = tid & 63;
    int n = blockIdx.x * 4 + wv;
    int beg = rowptr[n], end = rowptr[n + 1];
    int deg = end - beg;
    int h8 = l >> 3;
    int q = l & 7;

    float acc = 0.f;
    float4 av = make_float4(0, 0, 0, 0), ar = make_float4(0, 0, 0, 0);

    for (int base = beg; base < end; base += 64) {
        int cnt = min(64, end - base);
        int epre = 0, spre = 0;
        if (l < cnt) {
            int2 es = eidx2[base + l];
            epre = es.x; spre = es.y;
        }
        for (int b0 = 0; b0 < cnt; b0 += 8) {
            int bn = min(8, cnt - b0);
            float pwb[8];
            uint2 vvb[8];
#pragma unroll
            for (int p = 0; p < 8; ++p) {
                int idx = b0 + ((p < bn) ? p : (bn - 1));
                int e1 = __shfl(epre, idx, 64);
                int s1 = __shfl(spre, idx, 64);
                pwb[p] = (l < 24) ? pw[(size_t)e1 * 24 + l] : 0.f;
                vvb[p] = *(const uint2*)(valh + (size_t)s1 * 256 + l * 4);
            }
#pragma unroll
            for (int p = 0; p < 8; ++p) {
                if (p < bn) {
                    float tmp = pwb[p];
                    if (l < 24) acc += tmp;
                    float wV = __shfl(tmp, h8, 64);
                    float wR = __shfl(tmp, 8 + h8, 64);
                    float2 f0 = __half22float2(*(__half2*)&vvb[p].x);
                    float2 f1 = __half22float2(*(__half2*)&vvb[p].y);
                    av.x = fmaf(f0.x, wV, av.x); av.y = fmaf(f0.y, wV, av.y);
                    av.z = fmaf(f1.x, wV, av.z); av.w = fmaf(f1.y, wV, av.w);
                    ar.x = fmaf(f0.x, wR, ar.x); ar.y = fmaf(f0.y, wR, ar.y);
                    ar.z = fmaf(f1.x, wR, ar.z); ar.w = fmaf(f1.y, wR, ar.w);
                }
            }
        }
    }
    float dv = __shfl(acc, h8, 64) + EPSV;
    float drn = __shfl(acc, 8 + h8, 64) + EPSV;
    float rdv = 1.f / dv, rdr = 1.f / drn;
    av.x *= rdv; av.y *= rdv; av.z *= rdv; av.w *= rdv;
    ar.x *= rdr; ar.y *= rdr; ar.z *= rdr; ar.w *= rdr;

    float* cp = &cat[wv][h8 * 68 + q * 4];
    *(float4*)cp = av;
    *(float4*)(cp + 32) = ar;

    float dscale = 1.f / (float)(deg > 1 ? deg : 1);
    float gs = __shfl(acc, 16 + q, 64);
    if (l < 8) {
        float gl = g1[(size_t)n * 8 + l] + gs * dscale + gate_b[l];
        gate_lds[wv][l] = 1.f / (1.f + exp2f(-gl * LOG2E));
    }
    __syncthreads();

    int nd = tid & 3, oi = tid >> 2;
    int hh = oi >> 3, qq = oi & 7;
    float4 ho = *(const float4*)(Pb + oi * 4);
    const float* crow = &cat[nd][hh * 68];
    const float* wrow = Wp + (size_t)hh * 2048 + qq * 4;
#pragma unroll 4
    for (int d = 0; d < 64; ++d) {
        float c = crow[d];
        float4 w4 = *(const float4*)(wrow + d * 32);
        ho.x = fmaf(c, w4.x, ho.x); ho.y = fmaf(c, w4.y, ho.y);
        ho.z = fmaf(c, w4.z, ho.z); ho.w = fmaf(c, w4.w, ho.w);
    }
    float g = gate_lds[nd][hh];
    float4 fb = *(const float4*)(final_bias + oi * 4);
    float4 o;
    o.x = fmaf(ho.x, g, fb.x); o.y = fmaf(ho.y, g, fb.y);
    o.z = fmaf(ho.z, g, fb.z); o.w = fmaf(ho.w, g, fb.w);
    *(float4*)(out + (size_t)(blockIdx.x * 4 + nd) * 256 + oi * 4) = o;
}

extern "C" void kernel_launch(void* const* d_in, const int* in_sizes, int n_in,
                              void* d_out, int out_size, void* d_ws, size_t ws_size,
                              hipStream_t stream) {
    const float* inp         = (const float*)d_in[0];
    const float* W_value     = (const float*)d_in[2];
    const float* W_relation  = (const float*)d_in[3];
    const float* deprel_emb  = (const float*)d_in[4];
    const float* deparc_emb  = (const float*)d_in[5];
    const float* w_src       = (const float*)d_in[6];
    const float* w_tgt       = (const float*)d_in[7];
    const float* w_rel       = (const float*)d_in[8];
    const float* fpw         = (const float*)d_in[9];
    const float* fpb         = (const float*)d_in[10];
    const float* neighbor_w  = (const float*)d_in[11];
    const float* neighbor_b  = (const float*)d_in[12];
    const float* gate_w      = (const float*)d_in[13];
    const float* gate_b      = (const float*)d_in[14];
    const float* final_bias  = (const float*)d_in[15];
    const int*   edge_index  = (const int*)d_in[16];
    const int*   deprel_edge = (const int*)d_in[17];
    const int*   deparc_edge = (const int*)d_in[18];
    const int* srcArr = edge_index;
    const int* tgtArr = edge_index + N_EDGES;
    float* out = (float*)d_out;

    // workspace carve
    __half* valh = (__half*)d_ws;                                 // 10.24 MB
    unsigned short* Bt = (unsigned short*)(valh + 5120000);       // 160 KB
    float* bg2 = (float*)(Bt + 81920);                            // 8
    float* vs = bg2 + 8;
    float* vt = vs + 160000;
    float* g1 = vt + 160000;
    float* g2 = g1 + 160000;
    float* SA = g2 + 160000;
    float* SB = SA + 400;
    float* pw = SB + 32;                                          // 15.36 MB
    int* cnts = (int*)(pw + (size_t)N_EDGES * 24);                // 160,000
    int* rowptr = cnts + 160000;                                  // 20,001 (+1 pad)
    int2* eidx2 = (int2*)(rowptr + 20002);                        // 160,000 int2

    k_pre<<<913, 256, 0, stream>>>(W_value, neighbor_w, neighbor_b,
                                   w_src, w_tgt, gate_w, Bt, bg2,
                                   W_relation, w_rel, deprel_emb, deparc_emb, SA, SB,
                                   tgtArr, cnts);
    k_mid<<<1251, 256, 0, stream>>>(inp, Bt, bg2, valh, vs, vt, g1, g2, cnts, rowptr);
    k_post<<<1265, 256, 0, stream>>>(vs, vt, SA, SB, g2, srcArr, tgtArr,
                                     deprel_edge, deparc_edge, pw, rowptr, cnts, eidx2);
    k_agg<<<N_NODES / 4, 256, 0, stream>>>(valh, pw, g1, rowptr, eidx2,
                                           fpw, fpb, gate_b, final_bias, out);
}

// Round 10
// 239.633 us; speedup vs baseline: 1.0383x; 1.0383x over previous
//
#include <hip/hip_runtime.h>
#include <hip/hip_fp16.h>
#include <math.h>

#define N_NODES 20000
#define N_EDGES 160000
#define EPSV 1e-12f
#define SLOPE 0.2f
#define LOG2E 1.4426950408889634f

__device__ __forceinline__ float leaky(float x) { return x >= 0.f ? x : SLOPE * x; }

__device__ __forceinline__ unsigned short cvt_bf16(float f) {
    unsigned u = __float_as_uint(f);
    u = (u + 0x7FFFu + ((u >> 16) & 1u)) >> 16;
    return (unsigned short)u;
}
__device__ __forceinline__ unsigned pk2(float a, float b) {
    return (unsigned)cvt_bf16(a) | ((unsigned)cvt_bf16(b) << 16);
}

// fragment-ordered Bt index: column n (0..319), k (0..255)
__device__ __forceinline__ int btf_idx(int n, int k) {
    int w = n / 80, rem = n - w * 80, t = rem >> 4, l16 = rem & 15;
    int kk = k >> 5, c = k & 31, quad = c >> 3, e = c & 7;
    int lane = quad * 16 + l16;
    return (((w * 5 + t) * 8 + kk) * 64 + lane) * 8 + e;
}

typedef __attribute__((ext_vector_type(8))) short bf16x8;
typedef __attribute__((ext_vector_type(4))) float f32x4;

// ============ STAGE 1: fold (0..271) + rel (272) + count (273..912) ============
__global__ __launch_bounds__(256) void k_pre(
    const float* __restrict__ Wv, const float* __restrict__ Wn,
    const float* __restrict__ nbb, const float* __restrict__ wsrc,
    const float* __restrict__ wtgt, const float* __restrict__ gw,
    unsigned short* __restrict__ Btf, float* __restrict__ bg2,
    const float* __restrict__ Wrel, const float* __restrict__ wrel,
    const float* __restrict__ deprel_emb, const float* __restrict__ deparc_emb,
    float* __restrict__ SA, float* __restrict__ SB,
    const int* __restrict__ tgt, int* __restrict__ cnts)
{
    __shared__ float wr2[128 * 8];
    __shared__ int cnt[250];
    int k = threadIdx.x;
    int b = blockIdx.x;
    if (b < 256) {
        Btf[btf_idx(b, k)] = cvt_bf16(Wv[k * 256 + b]);
    } else if (b < 264) {
        int h = b - 256;
        float a_vs = 0.f, a_vt = 0.f, a_ng = 0.f;
        for (int d = 0; d < 32; ++d) {
            float w = Wv[k * 256 + h * 32 + d];
            a_vs = fmaf(w, wsrc[h * 32 + d], a_vs);
            a_vt = fmaf(w, wtgt[h * 32 + d], a_vt);
        }
        for (int j = 0; j < 256; ++j)
            a_ng = fmaf(Wn[k * 256 + j], gw[(256 + j) * 8 + h], a_ng);
        Btf[btf_idx(256 + h, k)] = cvt_bf16(a_vs);
        Btf[btf_idx(264 + h, k)] = cvt_bf16(a_vt);
        Btf[btf_idx(272 + h, k)] = cvt_bf16(gw[k * 8 + h]);
        Btf[btf_idx(280 + h, k)] = cvt_bf16(a_ng);
        if (k == 0) {
            float s = 0.f;
            for (int j = 0; j < 256; ++j) s = fmaf(nbb[j], gw[(256 + j) * 8 + h], s);
            bg2[h] = s;
        }
    } else if (b < 272) {
        int n0 = 288 + (b - 264) * 4;
        for (int i = 0; i < 4; ++i) Btf[btf_idx(n0 + i, k)] = 0;
    } else if (b == 272) {
        for (int i = k; i < 1024; i += 256) {
            int kk = i >> 3, h = i & 7;
            float acc = 0.f;
            for (int r = 0; r < 16; ++r)
                acc += Wrel[kk * 128 + h * 16 + r] * wrel[h * 16 + r];
            wr2[kk * 8 + h] = acc;
        }
        __syncthreads();
        for (int i = k; i < 50 * 8; i += 256) {
            int d = i >> 3, h = i & 7;
            float acc = 0.f;
            for (int kk = 0; kk < 64; ++kk) acc += deprel_emb[d * 64 + kk] * wr2[kk * 8 + h];
            SA[i] = acc;
        }
        for (int i = k; i < 4 * 8; i += 256) {
            int d = i >> 3, h = i & 7;
            float acc = 0.f;
            for (int kk = 0; kk < 64; ++kk) acc += deparc_emb[d * 64 + kk] * wr2[(64 + kk) * 8 + h];
            SB[i] = acc;
        }
    } else {
        int idx = b - 273;
        int slice = idx & 7, range = idx >> 3;
        int lo = range * 250;
        if (k < 250) cnt[k] = 0;
        __syncthreads();
        const int4* t4 = (const int4*)tgt;
        int i0 = slice * 5000;
#pragma unroll 4
        for (int i = k; i < 5000; i += 256) {
            int4 v = t4[i0 + i];
            unsigned a = (unsigned)(v.x - lo); if (a < 250u) atomicAdd(&cnt[a], 1);
            unsigned bb = (unsigned)(v.y - lo); if (bb < 250u) atomicAdd(&cnt[bb], 1);
            unsigned c = (unsigned)(v.z - lo); if (c < 250u) atomicAdd(&cnt[c], 1);
            unsigned d = (unsigned)(v.w - lo); if (d < 250u) atomicAdd(&cnt[d], 1);
        }
        __syncthreads();
        if (k < 250) cnts[(lo + k) * 8 + slice] = cnt[k];
    }
}

// ============ STAGE 2: mfma (0..1249) + scan (1250) ============
__global__ __launch_bounds__(256) void k_mid(
    const float* __restrict__ inp, const unsigned short* __restrict__ Btf,
    const float* __restrict__ bg2, __half* __restrict__ valh,
    float* __restrict__ vs, float* __restrict__ vt,
    float* __restrict__ g1, float* __restrict__ g2,
    const int* __restrict__ cnts, int* __restrict__ rowptr)
{
    __shared__ unsigned short degl[N_NODES];  // 40 KB (scan block only)
    __shared__ int wsum[4];
    int tid = threadIdx.x;
    if (blockIdx.x < 1250) {
        int wave = tid >> 6, lane = tid & 63;
        int quad = lane >> 4, l16 = lane & 15;
        int row0 = blockIdx.x * 16;
        const float* arow = inp + (size_t)(row0 + l16) * 256;
        bf16x8 afr[8];
#pragma unroll
        for (int kk = 0; kk < 8; ++kk) {
            float4 f0 = *(const float4*)(arow + kk * 32 + quad * 8);
            float4 f1 = *(const float4*)(arow + kk * 32 + quad * 8 + 4);
            union { unsigned u[4]; bf16x8 v; } cv;
            cv.u[0] = pk2(f0.x, f0.y); cv.u[1] = pk2(f0.z, f0.w);
            cv.u[2] = pk2(f1.x, f1.y); cv.u[3] = pk2(f1.z, f1.w);
            afr[kk] = cv.v;
        }
        f32x4 acc[5] = {};
#pragma unroll
        for (int kk = 0; kk < 8; ++kk) {
#pragma unroll
            for (int t = 0; t < 5; ++t) {
                bf16x8 bf = *(const bf16x8*)(Btf + (((wave * 5 + t) * 8 + kk) * 64 + lane) * 8);
                acc[t] = __builtin_amdgcn_mfma_f32_16x16x32_bf16(afr[kk], bf, acc[t], 0, 0, 0);
            }
        }
#pragma unroll
        for (int t = 0; t < 5; ++t) {
            int n = wave * 80 + t * 16 + l16;
#pragma unroll
            for (int r = 0; r < 4; ++r) {
                int row = row0 + quad * 4 + r;
                float v = acc[t][r];
                if (n < 256) {
                    valh[(size_t)row * 256 + n] = __float2half(v);
                } else if (n < 288) {
                    int c2 = n - 256, which = c2 >> 3, h = c2 & 7;
                    if (which == 3) v += bg2[h];
                    float* dst = (which == 0) ? vs : (which == 1) ? vt : (which == 2) ? g1 : g2;
                    dst[(size_t)row * 8 + h] = v;
                }
            }
        }
    } else {
        int lane = tid & 63, w = tid >> 6;
        for (int nn = tid; nn < N_NODES; nn += 256) {
            const int4* c4 = (const int4*)(cnts + (size_t)nn * 8);
            int4 a = c4[0], b = c4[1];
            degl[nn] = (unsigned short)(a.x + a.y + a.z + a.w + b.x + b.y + b.z + b.w);
        }
        __syncthreads();
        int start = tid * 79;
        int stop = min(start + 79, N_NODES);
        int s = 0;
        for (int i = start; i < stop; ++i) s += degl[i];
        int ps = s;
#pragma unroll
        for (int off = 1; off < 64; off <<= 1) {
            int x = __shfl_up(ps, off, 64);
            if (lane >= off) ps += x;
        }
        if (lane == 63) wsum[w] = ps;
        __syncthreads();
        if (tid == 0) {
            int a0 = wsum[0], a1 = wsum[1], a2 = wsum[2];
            wsum[0] = 0; wsum[1] = a0; wsum[2] = a0 + a1; wsum[3] = a0 + a1 + a2;
        }
        __syncthreads();
        int run = wsum[w] + ps - s;
        for (int i = start; i < stop; ++i) {
            rowptr[i] = run;
            run += degl[i];
        }
        if (tid == 255) rowptr[N_NODES] = run;
    }
}

// ============ STAGE 3: fill only -- int4 CSR records {src, deprel, deparc, 0} ============
__global__ __launch_bounds__(256) void k_fill(
    const int* __restrict__ src, const int* __restrict__ tgt,
    const int* __restrict__ deprel, const int* __restrict__ deparc,
    const int* __restrict__ rowptr, const int* __restrict__ cnts,
    int4* __restrict__ eidx4)
{
    __shared__ int cur[250];
    int tid = threadIdx.x;
    int slice = blockIdx.x & 7, range = blockIdx.x >> 3;
    int lo = range * 250;
    if (tid < 250) {
        int base = rowptr[lo + tid];
        const int* c = cnts + (size_t)(lo + tid) * 8;
        for (int s = 0; s < slice; ++s) base += c[s];
        cur[tid] = base;
    }
    __syncthreads();
    const int4* t4 = (const int4*)tgt;
    const int4* s4 = (const int4*)src;
    const int4* r4 = (const int4*)deprel;
    const int4* a4 = (const int4*)deparc;
    int i0 = slice * 5000;
    for (int i = tid; i < 5000; i += 256) {
        int4 v = t4[i0 + i];
        int4 sv = s4[i0 + i];
        int4 rv = r4[i0 + i];
        int4 av = a4[i0 + i];
        unsigned a = (unsigned)(v.x - lo); if (a < 250u) { int p = atomicAdd(&cur[a], 1); eidx4[p] = make_int4(sv.x, rv.x, av.x, 0); }
        unsigned b = (unsigned)(v.y - lo); if (b < 250u) { int p = atomicAdd(&cur[b], 1); eidx4[p] = make_int4(sv.y, rv.y, av.y, 0); }
        unsigned c = (unsigned)(v.z - lo); if (c < 250u) { int p = atomicAdd(&cur[c], 1); eidx4[p] = make_int4(sv.z, rv.z, av.z, 0); }
        unsigned d = (unsigned)(v.w - lo); if (d < 250u) { int p = atomicAdd(&cur[d], 1); eidx4[p] = make_int4(sv.w, rv.w, av.w, 0); }
    }
}

// ============ STAGE 4: aggregation with inline scores (L2 tables), batch-8 ============
__global__ __launch_bounds__(256) void k_agg(
    const __half* __restrict__ valh, const float* __restrict__ vs,
    const float* __restrict__ vt, const float* __restrict__ SA,
    const float* __restrict__ SB, const float* __restrict__ g2,
    const float* __restrict__ g1,
    const int* __restrict__ rowptr, const int4* __restrict__ eidx4,
    const float* __restrict__ Wp, const float* __restrict__ Pb,
    const float* __restrict__ gate_b, const float* __restrict__ final_bias,
    float* __restrict__ out)
{
    __shared__ float cat[4][548];
    __shared__ float gate_lds[4][8];
    int tid = threadIdx.x, wv = tid >> 6, l = tid & 63;
    int n = blockIdx.x * 4 + wv;
    int beg = rowptr[n], end = rowptr[n + 1];
    int deg = end - beg;
    int h8 = l >> 3;
    int q = l & 7;
    float vtq = vt[(size_t)n * 8 + q];
    bool isR = (l >= 8) && (l < 16);

    float acc = 0.f;
    float4 av = make_float4(0, 0, 0, 0), ar = make_float4(0, 0, 0, 0);

    for (int base = beg; base < end; base += 64) {
        int cnt = min(64, end - base);
        int4 rec = make_int4(0, 0, 0, 0);
        if (l < cnt) rec = eidx4[base + l];
        for (int b0 = 0; b0 < cnt; b0 += 8) {
            int bn = min(8, cnt - b0);
            float rawb[8];
            uint2 vvb[8];
#pragma unroll
            for (int p = 0; p < 8; ++p) {
                int idx = b0 + ((p < bn) ? p : (bn - 1));
                int s1 = __shfl(rec.x, idx, 64);
                int dr = __shfl(rec.y, idx, 64);
                int da = __shfl(rec.z, idx, 64);
                const float* tab = (l < 8) ? (vs + (size_t)s1 * 8)
                                 : (l < 16) ? (SA + dr * 8)
                                 : (l < 24) ? (g2 + (size_t)s1 * 8)
                                 : (l < 32) ? (SB + da * 8)
                                 : (vs + (size_t)s1 * 8);
                rawb[p] = tab[q];
                vvb[p] = *(const uint2*)(valh + (size_t)s1 * 256 + l * 4);
            }
#pragma unroll
            for (int p = 0; p < 8; ++p) {
                if (p < bn) {
                    float rawc = rawb[p];
                    float sb = __shfl(rawc, 24 + q, 64);
                    float sc = rawc + vtq + (isR ? sb : 0.f);
                    float tmp = (l < 16) ? exp2f(leaky(sc) * LOG2E) : rawc;
                    if (l < 24) acc += tmp;
                    float wV = __shfl(tmp, h8, 64);
                    float wR = __shfl(tmp, 8 + h8, 64);
                    float2 f0 = __half22float2(*(__half2*)&vvb[p].x);
                    float2 f1 = __half22float2(*(__half2*)&vvb[p].y);
                    av.x = fmaf(f0.x, wV, av.x); av.y = fmaf(f0.y, wV, av.y);
                    av.z = fmaf(f1.x, wV, av.z); av.w = fmaf(f1.y, wV, av.w);
                    ar.x = fmaf(f0.x, wR, ar.x); ar.y = fmaf(f0.y, wR, ar.y);
                    ar.z = fmaf(f1.x, wR, ar.z); ar.w = fmaf(f1.y, wR, ar.w);
                }
            }
        }
    }
    float dv = __shfl(acc, h8, 64) + EPSV;
    float drn = __shfl(acc, 8 + h8, 64) + EPSV;
    float rdv = 1.f / dv, rdr = 1.f / drn;
    av.x *= rdv; av.y *= rdv; av.z *= rdv; av.w *= rdv;
    ar.x *= rdr; ar.y *= rdr; ar.z *= rdr; ar.w *= rdr;

    float* cp = &cat[wv][h8 * 68 + q * 4];
    *(float4*)cp = av;
    *(float4*)(cp + 32) = ar;

    float dscale = 1.f / (float)(deg > 1 ? deg : 1);
    float gs = __shfl(acc, 16 + q, 64);
    if (l < 8) {
        float gl = g1[(size_t)n * 8 + l] + gs * dscale + gate_b[l];
        gate_lds[wv][l] = 1.f / (1.f + exp2f(-gl * LOG2E));
    }
    __syncthreads();

    int nd = tid & 3, oi = tid >> 2;
    int hh = oi >> 3, qq = oi & 7;
    float4 ho = *(const float4*)(Pb + oi * 4);
    const float* crow = &cat[nd][hh * 68];
    const float* wrow = Wp + (size_t)hh * 2048 + qq * 4;
#pragma unroll 4
    for (int d = 0; d < 64; ++d) {
        float c = crow[d];
        float4 w4 = *(const float4*)(wrow + d * 32);
        ho.x = fmaf(c, w4.x, ho.x); ho.y = fmaf(c, w4.y, ho.y);
        ho.z = fmaf(c, w4.z, ho.z); ho.w = fmaf(c, w4.w, ho.w);
    }
    float g = gate_lds[nd][hh];
    float4 fb = *(const float4*)(final_bias + oi * 4);
    float4 o;
    o.x = fmaf(ho.x, g, fb.x); o.y = fmaf(ho.y, g, fb.y);
    o.z = fmaf(ho.z, g, fb.z); o.w = fmaf(ho.w, g, fb.w);
    *(float4*)(out + (size_t)(blockIdx.x * 4 + nd) * 256 + oi * 4) = o;
}

extern "C" void kernel_launch(void* const* d_in, const int* in_sizes, int n_in,
                              void* d_out, int out_size, void* d_ws, size_t ws_size,
                              hipStream_t stream) {
    const float* inp         = (const float*)d_in[0];
    const float* W_value     = (const float*)d_in[2];
    const float* W_relation  = (const float*)d_in[3];
    const float* deprel_emb  = (const float*)d_in[4];
    const float* deparc_emb  = (const float*)d_in[5];
    const float* w_src       = (const float*)d_in[6];
    const float* w_tgt       = (const float*)d_in[7];
    const float* w_rel       = (const float*)d_in[8];
    const float* fpw         = (const float*)d_in[9];
    const float* fpb         = (const float*)d_in[10];
    const float* neighbor_w  = (const float*)d_in[11];
    const float* neighbor_b  = (const float*)d_in[12];
    const float* gate_w      = (const float*)d_in[13];
    const float* gate_b      = (const float*)d_in[14];
    const float* final_bias  = (const float*)d_in[15];
    const int*   edge_index  = (const int*)d_in[16];
    const int*   deprel_edge = (const int*)d_in[17];
    const int*   deparc_edge = (const int*)d_in[18];
    const int* srcArr = edge_index;
    const int* tgtArr = edge_index + N_EDGES;
    float* out = (float*)d_out;

    // workspace carve
    __half* valh = (__half*)d_ws;                                 // 10.24 MB
    unsigned short* Btf = (unsigned short*)(valh + 5120000);      // 160 KB
    float* bg2 = (float*)(Btf + 81920);                           // 8
    float* vs = bg2 + 8;
    float* vt = vs + 160000;
    float* g1 = vt + 160000;
    float* g2 = g1 + 160000;
    float* SA = g2 + 160000;
    float* SB = SA + 400;
    int* cnts = (int*)(SB + 32);                                  // 160,000
    int* rowptr = cnts + 160000;                                  // 20,004 (padded)
    int4* eidx4 = (int4*)(rowptr + 20004);                        // 160,000 int4

    k_pre<<<913, 256, 0, stream>>>(W_value, neighbor_w, neighbor_b,
                                   w_src, w_tgt, gate_w, Btf, bg2,
                                   W_relation, w_rel, deprel_emb, deparc_emb, SA, SB,
                                   tgtArr, cnts);
    k_mid<<<1251, 256, 0, stream>>>(inp, Btf, bg2, valh, vs, vt, g1, g2, cnts, rowptr);
    k_fill<<<640, 256, 0, stream>>>(srcArr, tgtArr, deprel_edge, deparc_edge,
                                    rowptr, cnts, eidx4);
    k_agg<<<N_NODES / 4, 256, 0, stream>>>(valh, vs, vt, SA, SB, g2, g1,
                                           rowptr, eidx4,
                                           fpw, fpb, gate_b, final_bias, out);
}